// Round 2
// baseline (358.899 us; speedup 1.0000x reference)
//
#include <hip/hip_runtime.h>
#include <hip/hip_bf16.h>

// DySample: 1x1 conv (8 ch) -> pixel_shuffle(2) -> grid offsets -> bilinear grid_sample
// B=16, C=256, H=W=64, r=2, out (16,256,128,128).
//
// R1 post-mortem: NaN output is only explainable by misreading float32 inputs
// as bf16 (low mantissa halves hit bf16-NaN exponent patterns -> conv NaN ->
// coords NaN -> sample weights NaN). This version detects the dtype on-device
// (k_detect) and runs matching load/store paths. flag=1 -> bf16, flag=0 -> f32.

#define NB 16
#define NC 256
#define NH 64
#define NW 64
#define NHO 128
#define NWO 128
#define PLANE (NH*NW)      // 4096
#define OPLANE (NHO*NWO)   // 16384

static __device__ __forceinline__ float bf2f(unsigned short u) {
    return __uint_as_float(((unsigned int)u) << 16);
}
static __device__ __forceinline__ unsigned short f2bf(float f) {
    unsigned int u = __float_as_uint(f);
    u = (u + 0x7FFFu + ((u >> 16) & 1u)) >> 16;   // RNE; finite inputs only
    return (unsigned short)u;
}
static __device__ __forceinline__ uint4 pack8(const float* r) {
    uint4 u;
    u.x = (unsigned)f2bf(r[0]) | ((unsigned)f2bf(r[1]) << 16);
    u.y = (unsigned)f2bf(r[2]) | ((unsigned)f2bf(r[3]) << 16);
    u.z = (unsigned)f2bf(r[4]) | ((unsigned)f2bf(r[5]) << 16);
    u.w = (unsigned)f2bf(r[6]) | ((unsigned)f2bf(r[7]) << 16);
    return u;
}

// Classify input dtype. For each 32-bit word of x, test whether BOTH 16-bit
// halves, viewed as bf16, have exponent in [97,143] (|v| in [2^-30, 2^16]).
// Genuine bf16 N(0,1) data: ~100% of words pass. float32 data misread: the
// low half is uniform-random mantissa bits -> ~18% pass. Threshold 75%.
__global__ void k_detect(const unsigned int* __restrict__ xw, int* __restrict__ flag)
{
    __shared__ int cnt;
    if (threadIdx.x == 0) cnt = 0;
    __syncthreads();
    unsigned int w = xw[threadIdx.x];
    int el = (int)((w >> 7)  & 0xFFu);
    int eh = (int)((w >> 23) & 0xFFu);
    bool ok = (el >= 97 && el <= 143) && (eh >= 97 && eh <= 143);
    if (ok) atomicAdd(&cnt, 1);
    __syncthreads();
    if (threadIdx.x == 0) *flag = (cnt >= 192) ? 1 : 0;
}

// Kernel 1: per input pixel, 8-channel 1x1 conv, pixel-shuffle to 4 output
// pixels, add base grid, emit absolute sample coords (ix, iy) as float2.
__global__ __launch_bounds__(128) void k_offsets(
    const void* __restrict__ x_,
    const void* __restrict__ w_,
    const void* __restrict__ b_,
    float2* __restrict__ coords,
    const int* __restrict__ flag)
{
    __shared__ float4 wl4[NC * 2];          // 16B-aligned; wl[c*8+o] = weight[o][c]
    float* wl = (float*)wl4;
    const int tid = threadIdx.x;
    const int isbf = *flag;

    if (isbf) {
        const unsigned short* weight = (const unsigned short*)w_;
        #pragma unroll
        for (int i = 0; i < 16; ++i) {
            int idx = tid * 16 + i;
            int c = idx >> 3, o = idx & 7;
            wl[idx] = bf2f(weight[o * NC + c]);
        }
    } else {
        const float* weight = (const float*)w_;
        #pragma unroll
        for (int i = 0; i < 16; ++i) {
            int idx = tid * 16 + i;
            int c = idx >> 3, o = idx & 7;
            wl[idx] = weight[o * NC + c];
        }
    }
    __syncthreads();

    float bv[8];
    if (isbf) {
        const unsigned short* bias = (const unsigned short*)b_;
        #pragma unroll
        for (int o = 0; o < 8; ++o) bv[o] = bf2f(bias[o]);
    } else {
        const float* bias = (const float*)b_;
        #pragma unroll
        for (int o = 0; o < 8; ++o) bv[o] = bias[o];
    }

    const int p0 = blockIdx.x * 256 + tid;   // two pixels per thread
    const int p1 = p0 + 128;
    const int b0 = p0 >> 12, h0 = (p0 >> 6) & 63, w0 = p0 & 63;
    const int b1 = p1 >> 12, h1 = (p1 >> 6) & 63, w1 = p1 & 63;
    const size_t off0 = (size_t)b0 * NC * PLANE + h0 * NW + w0;
    const size_t off1 = (size_t)b1 * NC * PLANE + h1 * NW + w1;

    float a0[8], a1[8];
    #pragma unroll
    for (int o = 0; o < 8; ++o) { a0[o] = 0.0f; a1[o] = 0.0f; }

    if (isbf) {
        const unsigned short* xp0 = (const unsigned short*)x_ + off0;
        const unsigned short* xp1 = (const unsigned short*)x_ + off1;
        #pragma unroll 4
        for (int c = 0; c < NC; ++c) {
            float4 wA = wl4[c * 2], wB = wl4[c * 2 + 1];
            float wv[8] = { wA.x, wA.y, wA.z, wA.w, wB.x, wB.y, wB.z, wB.w };
            float xv0 = bf2f(xp0[c * PLANE]);
            float xv1 = bf2f(xp1[c * PLANE]);
            #pragma unroll
            for (int o = 0; o < 8; ++o) {
                a0[o] = fmaf(xv0, wv[o], a0[o]);
                a1[o] = fmaf(xv1, wv[o], a1[o]);
            }
        }
    } else {
        const float* xp0 = (const float*)x_ + off0;
        const float* xp1 = (const float*)x_ + off1;
        #pragma unroll 4
        for (int c = 0; c < NC; ++c) {
            float4 wA = wl4[c * 2], wB = wl4[c * 2 + 1];
            float wv[8] = { wA.x, wA.y, wA.z, wA.w, wB.x, wB.y, wB.z, wB.w };
            float xv0 = xp0[c * PLANE];
            float xv1 = xp1[c * PLANE];
            #pragma unroll
            for (int o = 0; o < 8; ++o) {
                a0[o] = fmaf(xv0, wv[o], a0[o]);
                a1[o] = fmaf(xv1, wv[o], a1[o]);
            }
        }
    }
    #pragma unroll
    for (int o = 0; o < 8; ++o) { a0[o] += bv[o]; a1[o] += bv[o]; }

    // pixel-shuffle: conv channel co*4 + ry*2 + rx -> out pixel (2h+ry, 2w+rx)
    // grid[...,0] = gh (row linspace) + ch0 -> ix (W axis); [...,1] = gw + ch1 -> iy
    #pragma unroll
    for (int ry = 0; ry < 2; ++ry) {
        #pragma unroll
        for (int rx = 0; rx < 2; ++rx) {
            int q = ry * 2 + rx;
            {
                int ho = 2 * h0 + ry, wo = 2 * w0 + rx;
                float gh = fmaf((float)ho, 2.0f / 127.0f, -1.0f);
                float gw = fmaf((float)wo, 2.0f / 127.0f, -1.0f);
                float ix = ((gh + a0[q] + 1.0f) * 64.0f - 1.0f) * 0.5f;
                float iy = ((gw + a0[q + 4] + 1.0f) * 64.0f - 1.0f) * 0.5f;
                coords[(size_t)b0 * OPLANE + ho * NWO + wo] = make_float2(ix, iy);
            }
            {
                int ho = 2 * h1 + ry, wo = 2 * w1 + rx;
                float gh = fmaf((float)ho, 2.0f / 127.0f, -1.0f);
                float gw = fmaf((float)wo, 2.0f / 127.0f, -1.0f);
                float ix = ((gh + a1[q] + 1.0f) * 64.0f - 1.0f) * 0.5f;
                float iy = ((gw + a1[q + 4] + 1.0f) * 64.0f - 1.0f) * 0.5f;
                coords[(size_t)b1 * OPLANE + ho * NWO + wo] = make_float2(ix, iy);
            }
        }
    }
}

// Kernel 2: one block = (b, 4-channel group). 4 planes interleaved in LDS as
// float4 (one ds_read_b128 = tap for 4 channels). Column rotation
// x' = (x + (y>>2)) & 63 breaks the stride-4-rows bank-conflict pattern.
__global__ __launch_bounds__(256) void k_sample(
    const void* __restrict__ x_,
    const float2* __restrict__ coords,
    void* __restrict__ out_,
    const int* __restrict__ flag)
{
    __shared__ float4 plane[PLANE];   // 64 KiB
    const int tid = threadIdx.x;
    const int blk = blockIdx.x;
    const int g = blk & 63;          // channel group (4 channels)
    const int b = blk >> 6;
    const int isbf = *flag;

    const size_t chbase = (size_t)(b * NC + g * 4) * PLANE;
    if (isbf) {
        const unsigned short* xb = (const unsigned short*)x_ + chbase;
        #pragma unroll
        for (int i = 0; i < 16; ++i) {
            int pos = i * 256 + tid;
            float4 v;
            v.x = bf2f(xb[pos]);
            v.y = bf2f(xb[PLANE + pos]);
            v.z = bf2f(xb[2 * PLANE + pos]);
            v.w = bf2f(xb[3 * PLANE + pos]);
            int y = pos >> 6;
            plane[(y << 6) | ((pos + (y >> 2)) & 63)] = v;
        }
    } else {
        const float* xb = (const float*)x_ + chbase;
        #pragma unroll
        for (int i = 0; i < 16; ++i) {
            int pos = i * 256 + tid;
            float4 v;
            v.x = xb[pos];
            v.y = xb[PLANE + pos];
            v.z = xb[2 * PLANE + pos];
            v.w = xb[3 * PLANE + pos];
            int y = pos >> 6;
            plane[(y << 6) | ((pos + (y >> 2)) & 63)] = v;
        }
    }
    __syncthreads();

    const float2* cb = coords + (size_t)b * OPLANE;
    const size_t obase = (size_t)(b * NC + g * 4) * OPLANE;

    #pragma unroll 1
    for (int it = 0; it < 8; ++it) {
        const int base = it * 2048 + tid * 8;   // 8 consecutive output pixels
        float r0[8], r1[8], r2[8], r3[8];
        #pragma unroll
        for (int j = 0; j < 8; ++j) {
            float2 cd = cb[base + j];
            float ix = cd.x, iy = cd.y;
            float fx0 = floorf(ix), fy0 = floorf(iy);
            float wx1 = ix - fx0, wy1 = iy - fy0;
            float wx0 = 1.0f - wx1, wy0 = 1.0f - wy1;
            int x0 = (int)fx0, y0 = (int)fy0;
            int x1 = x0 + 1, y1 = y0 + 1;
            bool vx0 = (unsigned)x0 < 64u, vx1 = (unsigned)x1 < 64u;
            bool vy0 = (unsigned)y0 < 64u, vy1 = (unsigned)y1 < 64u;
            float w00 = (vy0 & vx0) ? wy0 * wx0 : 0.0f;
            float w01 = (vy0 & vx1) ? wy0 * wx1 : 0.0f;
            float w10 = (vy1 & vx0) ? wy1 * wx0 : 0.0f;
            float w11 = (vy1 & vx1) ? wy1 * wx1 : 0.0f;
            int x0c = min(max(x0, 0), 63), x1c = min(max(x1, 0), 63);
            int y0c = min(max(y0, 0), 63), y1c = min(max(y1, 0), 63);
            int ry0 = y0c >> 2, ry1 = y1c >> 2;
            float4 a00 = plane[(y0c << 6) | ((x0c + ry0) & 63)];
            float4 a01 = plane[(y0c << 6) | ((x1c + ry0) & 63)];
            float4 a10 = plane[(y1c << 6) | ((x0c + ry1) & 63)];
            float4 a11 = plane[(y1c << 6) | ((x1c + ry1) & 63)];
            r0[j] = w00 * a00.x + w01 * a01.x + w10 * a10.x + w11 * a11.x;
            r1[j] = w00 * a00.y + w01 * a01.y + w10 * a10.y + w11 * a11.y;
            r2[j] = w00 * a00.z + w01 * a01.z + w10 * a10.z + w11 * a11.z;
            r3[j] = w00 * a00.w + w01 * a01.w + w10 * a10.w + w11 * a11.w;
        }
        if (isbf) {
            unsigned short* ob = (unsigned short*)out_ + obase;
            *reinterpret_cast<uint4*>(ob + base)              = pack8(r0);
            *reinterpret_cast<uint4*>(ob + OPLANE + base)     = pack8(r1);
            *reinterpret_cast<uint4*>(ob + 2 * OPLANE + base) = pack8(r2);
            *reinterpret_cast<uint4*>(ob + 3 * OPLANE + base) = pack8(r3);
        } else {
            float* ob = (float*)out_ + obase;
            #pragma unroll
            for (int ch = 0; ch < 4; ++ch) {
                const float* rr = (ch == 0) ? r0 : (ch == 1) ? r1 : (ch == 2) ? r2 : r3;
                *reinterpret_cast<float4*>(ob + ch * OPLANE + base)     = make_float4(rr[0], rr[1], rr[2], rr[3]);
                *reinterpret_cast<float4*>(ob + ch * OPLANE + base + 4) = make_float4(rr[4], rr[5], rr[6], rr[7]);
            }
        }
    }
}

extern "C" void kernel_launch(void* const* d_in, const int* in_sizes, int n_in,
                              void* d_out, int out_size, void* d_ws, size_t ws_size,
                              hipStream_t stream)
{
    int* flag = (int*)d_ws;                               // 4 B flag at d_ws+0
    float2* coords = (float2*)((char*)d_ws + 256);        // 2 MiB coords at +256

    hipLaunchKernelGGL(k_detect, dim3(1), dim3(256), 0, stream,
                       (const unsigned int*)d_in[0], flag);
    hipLaunchKernelGGL(k_offsets, dim3(256), dim3(128), 0, stream,
                       d_in[0], d_in[1], d_in[2], coords, flag);
    hipLaunchKernelGGL(k_sample, dim3(NB * 64), dim3(256), 0, stream,
                       d_in[0], coords, d_out, flag);
}

// Round 3
// 337.702 us; speedup vs baseline: 1.0628x; 1.0628x over previous
//
#include <hip/hip_runtime.h>

// DySample (f32): 1x1 conv (8 ch) -> pixel_shuffle(2) -> grid offsets -> bilinear
// grid_sample. B=16, C=256, H=W=64, r=2, out (16,256,128,128) float32.
//
// R2 post-mortem: inputs confirmed float32. 359 us was LDS bank conflicts in
// k_sample (8-px-per-thread => lane x-stride 4 => 2 of 8 float4 bank groups)
// plus a latency-bound, under-occupied k_offsets. Fix: 2 px/thread (x-stride 1,
// bank-optimal), 512-thr blocks; k_offsets rebuilt with 4-way channel split.

#define NB 16
#define NC 256
#define NH 64
#define NW 64
#define NHO 128
#define NWO 128
#define PLANE (NH*NW)      // 4096
#define OPLANE (NHO*NWO)   // 16384

// One block per input row (b,h). 256 thr: qid=tid>>6 picks a 64-channel
// quarter, w=tid&63 the pixel. Each thread partial-sums 64 channels; LDS
// reduce across quarters; wave 0 finalizes the 4 shuffled output coords.
__global__ __launch_bounds__(256, 4) void k_offsets(
    const float* __restrict__ x,
    const float* __restrict__ weight,
    const float* __restrict__ bias,
    float2* __restrict__ coords)
{
    __shared__ float4 wl4[NC * 2];      // wl[c*8+o] = weight[o][c], 8 KiB
    __shared__ float red[4][64][8];     // 8 KiB
    float* wl = (float*)wl4;
    const int tid = threadIdx.x;
    const int qid = tid >> 6, w = tid & 63;
    const int row = blockIdx.x;         // 1024 rows total
    const int b = row >> 6, h = row & 63;

    #pragma unroll
    for (int i = 0; i < 8; ++i) {
        int idx = tid * 8 + i;
        wl[idx] = weight[(idx & 7) * NC + (idx >> 3)];
    }
    __syncthreads();

    const float* xp = x + ((size_t)b * NC + (size_t)qid * 64) * PLANE + h * NW + w;
    float acc[8];
    #pragma unroll
    for (int o = 0; o < 8; ++o) acc[o] = 0.0f;

    #pragma unroll 8
    for (int i = 0; i < 64; ++i) {
        float xv = xp[(size_t)i * PLANE];
        float4 wA = wl4[(qid * 64 + i) * 2];
        float4 wB = wl4[(qid * 64 + i) * 2 + 1];
        acc[0] = fmaf(xv, wA.x, acc[0]);
        acc[1] = fmaf(xv, wA.y, acc[1]);
        acc[2] = fmaf(xv, wA.z, acc[2]);
        acc[3] = fmaf(xv, wA.w, acc[3]);
        acc[4] = fmaf(xv, wB.x, acc[4]);
        acc[5] = fmaf(xv, wB.y, acc[5]);
        acc[6] = fmaf(xv, wB.z, acc[6]);
        acc[7] = fmaf(xv, wB.w, acc[7]);
    }
    #pragma unroll
    for (int o = 0; o < 8; ++o) red[qid][w][o] = acc[o];
    __syncthreads();

    if (tid < 64) {
        float s[8];
        #pragma unroll
        for (int o = 0; o < 8; ++o)
            s[o] = red[0][tid][o] + red[1][tid][o] + red[2][tid][o] + red[3][tid][o]
                 + bias[o];
        // pixel_shuffle: conv ch q=ry*2+rx -> out px (2h+ry, 2w+rx); ch q adds
        // to grid[...,0] (x-coord, from row linspace gh); ch q+4 -> y-coord.
        float2* cb = coords + (size_t)b * OPLANE;
        #pragma unroll
        for (int ry = 0; ry < 2; ++ry) {
            int ho = 2 * h + ry;
            float gh = fmaf((float)ho, 2.0f / 127.0f, -1.0f);
            float4 st;
            {
                int wo = 2 * tid;
                float gw = fmaf((float)wo, 2.0f / 127.0f, -1.0f);
                int q = ry * 2;
                st.x = ((gh + s[q] + 1.0f) * 64.0f - 1.0f) * 0.5f;       // ix
                st.y = ((gw + s[q + 4] + 1.0f) * 64.0f - 1.0f) * 0.5f;   // iy
            }
            {
                int wo = 2 * tid + 1;
                float gw = fmaf((float)wo, 2.0f / 127.0f, -1.0f);
                int q = ry * 2 + 1;
                st.z = ((gh + s[q] + 1.0f) * 64.0f - 1.0f) * 0.5f;
                st.w = ((gw + s[q + 4] + 1.0f) * 64.0f - 1.0f) * 0.5f;
            }
            *reinterpret_cast<float4*>(cb + ho * NWO + 2 * tid) = st;
        }
    }
}

// Bilinear tap blend for a 4-channel float4 plane in LDS.
static __device__ __forceinline__ float4 samp4(const float4* __restrict__ plane,
                                               float ix, float iy)
{
    float fx0 = floorf(ix), fy0 = floorf(iy);
    float wx1 = ix - fx0, wy1 = iy - fy0;
    float wx0 = 1.0f - wx1, wy0 = 1.0f - wy1;
    int x0 = (int)fx0, y0 = (int)fy0;
    int x1 = x0 + 1, y1 = y0 + 1;
    bool vx0 = (unsigned)x0 < 64u, vx1 = (unsigned)x1 < 64u;
    bool vy0 = (unsigned)y0 < 64u, vy1 = (unsigned)y1 < 64u;
    float w00 = (vy0 & vx0) ? wy0 * wx0 : 0.0f;
    float w01 = (vy0 & vx1) ? wy0 * wx1 : 0.0f;
    float w10 = (vy1 & vx0) ? wy1 * wx0 : 0.0f;
    float w11 = (vy1 & vx1) ? wy1 * wx1 : 0.0f;
    int x0c = min(max(x0, 0), 63), x1c = min(max(x1, 0), 63);
    int y0c = min(max(y0, 0), 63), y1c = min(max(y1, 0), 63);
    float4 a00 = plane[(y0c << 6) | x0c];
    float4 a01 = plane[(y0c << 6) | x1c];
    float4 a10 = plane[(y1c << 6) | x0c];
    float4 a11 = plane[(y1c << 6) | x1c];
    float4 r;
    r.x = w00 * a00.x + w01 * a01.x + w10 * a10.x + w11 * a11.x;
    r.y = w00 * a00.y + w01 * a01.y + w10 * a10.y + w11 * a11.y;
    r.z = w00 * a00.z + w01 * a01.z + w10 * a10.z + w11 * a11.z;
    r.w = w00 * a00.w + w01 * a01.w + w10 * a10.w + w11 * a11.w;
    return r;
}

// One block = (b, 4-channel group); 4 planes interleaved in LDS as float4.
// 512 thr, 2 consecutive output px per thread per iter => lane x-stride 1
// => float4 bank groups tile all 32 banks (conflict-free optimum).
__global__ __launch_bounds__(512, 4) void k_sample(
    const float* __restrict__ x,
    const float2* __restrict__ coords,
    float* __restrict__ out)
{
    __shared__ float4 plane[PLANE];   // 64 KiB
    const int tid = threadIdx.x;
    const int g = blockIdx.x & 63;    // channel group
    const int b = blockIdx.x >> 6;

    const float* xb = x + ((size_t)(b * NC + g * 4)) * PLANE;
    #pragma unroll
    for (int i = 0; i < 8; ++i) {
        int pos = i * 512 + tid;
        float4 v;
        v.x = xb[pos];
        v.y = xb[PLANE + pos];
        v.z = xb[2 * PLANE + pos];
        v.w = xb[3 * PLANE + pos];
        plane[pos] = v;
    }
    __syncthreads();

    const float4* cb4 = (const float4*)(coords + (size_t)b * OPLANE);
    float* ob = out + ((size_t)(b * NC + g * 4)) * OPLANE;

    #pragma unroll 1
    for (int it = 0; it < 16; ++it) {
        const int base = it * 1024 + tid * 2;     // 2 consecutive output px
        float4 cd = cb4[it * 512 + tid];          // (ix0,iy0,ix1,iy1)
        float4 p0 = samp4(plane, cd.x, cd.y);
        float4 p1 = samp4(plane, cd.z, cd.w);
        *reinterpret_cast<float2*>(ob + base)              = make_float2(p0.x, p1.x);
        *reinterpret_cast<float2*>(ob + OPLANE + base)     = make_float2(p0.y, p1.y);
        *reinterpret_cast<float2*>(ob + 2 * OPLANE + base) = make_float2(p0.z, p1.z);
        *reinterpret_cast<float2*>(ob + 3 * OPLANE + base) = make_float2(p0.w, p1.w);
    }
}

extern "C" void kernel_launch(void* const* d_in, const int* in_sizes, int n_in,
                              void* d_out, int out_size, void* d_ws, size_t ws_size,
                              hipStream_t stream)
{
    const float* x      = (const float*)d_in[0];
    const float* weight = (const float*)d_in[1];
    const float* bias   = (const float*)d_in[2];
    float* out = (float*)d_out;
    float2* coords = (float2*)d_ws;   // 16*16384*8 B = 2 MiB

    hipLaunchKernelGGL(k_offsets, dim3(NB * NH), dim3(256), 0, stream,
                       x, weight, bias, coords);
    hipLaunchKernelGGL(k_sample, dim3(NB * 64), dim3(512), 0, stream,
                       x, coords, out);
}